// Round 11
// baseline (11095.445 us; speedup 1.0000x reference)
//
#include <hip/hip_runtime.h>
#include <stdint.h>
#include <stddef.h>

#define T_SEQ  512
#define NBATCH 64
#define EMBED  512
#define HIDDEN 1024
#define VOCAB  32000
#define NWG    128                    // 64 L0 WGs + 64 L1 WGs, 256 thr each
#define NTHR   256
#define AGENT  __HIP_MEMORY_SCOPE_AGENT
#define RING   128                    // h ring slots: [64][ h1(1024) | h0(1024) ] bf16
#define SLOT_E (NBATCH * 2048)
#define RB     120                    // L0 WAR: wait L1@(t-RB) before writing slot t+1
#define SENT   0xFFFFFFFFu

#define RST   66                      // reduce-buffer row stride (floats)
#define PBUF  (64 * RST)              // one wave's partial: 64 rows x 64 batch

// bf16 weight staging offsets (elements) inside wb
#define L0G   1572864                 // 1024*1536 per gate
#define L1G   2097152                 // 1024*2048 per gate
#define L1OFF 6291456                 // 4*L0G

typedef __attribute__((ext_vector_type(8))) short short8;
typedef __attribute__((ext_vector_type(4))) float f32x4;

__device__ __forceinline__ unsigned short f2bf(float x) {
  union { float f; unsigned u; } v; v.f = x;
  unsigned r = v.u + 0x7FFFu + ((v.u >> 16) & 1u);   // round-to-nearest-even
  return (unsigned short)(r >> 16);
}
__device__ __forceinline__ float sigm(float x) { return 1.0f / (1.0f + __expf(-x)); }
__device__ __forceinline__ float tanh_(float x) {
  float e = __expf(2.0f * x);
  return 1.0f - 2.0f / (e + 1.0f);
}

// 16B MALL-coherent load as two 8B relaxed agent atomics (bypass stale L2;
// compiler manages waitcnt and pipelines them).
__device__ __forceinline__ short8 ldb16(const unsigned short* p) {
  union { unsigned long long q[2]; short8 v; } u;
  u.q[0] = __hip_atomic_load((unsigned long long*)p,       __ATOMIC_RELAXED, AGENT);
  u.q[1] = __hip_atomic_load((unsigned long long*)(p + 4), __ATOMIC_RELAXED, AGENT);
  return u.v;
}

// 64-lane parallel canary poll: lane w watches producer-WG w of (idx = t*2+layer).
__device__ __forceinline__ void pollcan(unsigned* can, int idx, int lane) {
  unsigned* cp = can + (idx << 6);
  unsigned v = __hip_atomic_load(cp + lane, __ATOMIC_RELAXED, AGENT);
  while (__any(v == SENT)) {
    __builtin_amdgcn_s_sleep(1);
    v = __hip_atomic_load(cp + lane, __ATOMIC_RELAXED, AGENT);
  }
  __builtin_amdgcn_fence(__ATOMIC_ACQUIRE, "workgroup");  // compile-order gate
  asm volatile("" ::: "memory");
}

// ---------------- embedding gather + bf16 cast: xs[t][b][e] ----------------
__global__ void embed_k(const int* __restrict__ texts, const float* __restrict__ emb,
                        unsigned short* __restrict__ xs) {
  const int bid = blockIdx.x;          // t*64 + b
  const int t = bid >> 6, b = bid & 63;
  const int row = texts[b * T_SEQ + t];
  const float* src = emb + (size_t)row * EMBED;
  const int e = threadIdx.x * 2;
  float2 v = *(const float2*)(src + e);
  unsigned pk = (unsigned)f2bf(v.x) | ((unsigned)f2bf(v.y) << 16);
  *(unsigned*)(xs + (size_t)bid * EMBED + e) = pk;
}

// ---------------- weights f32 -> bf16 staging ----------------
__global__ void wcast_k(const float* __restrict__ f0, const float* __restrict__ f1,
                        const float* __restrict__ f2, const float* __restrict__ f3,
                        const float* __restrict__ f4, const float* __restrict__ f5,
                        const float* __restrict__ f6, const float* __restrict__ f7,
                        unsigned short* __restrict__ wb) {
  const int b = blockIdx.x;
  const float* src; size_t off, dst;
  if (b < 3072) {                      // L0: 4 gates x 768 blocks
    const int g = b / 768;
    src = (g == 0) ? f0 : (g == 1) ? f1 : (g == 2) ? f2 : f3;
    off = (size_t)(b % 768) * 2048;
    dst = (size_t)g * L0G + off;
  } else {                             // L1: 4 gates x 1024 blocks
    const int b2 = b - 3072, g = b2 / 1024;
    src = (g == 0) ? f4 : (g == 1) ? f5 : (g == 2) ? f6 : f7;
    off = (size_t)(b2 % 1024) * 2048;
    dst = (size_t)L1OFF + (size_t)g * L1G + off;
  }
  const size_t i = off + (size_t)threadIdx.x * 8;
  f32x4 lo = *(const f32x4*)(src + i);
  f32x4 hi = *(const f32x4*)(src + i + 4);
  short8 v;
  v[0] = (short)f2bf(lo[0]); v[1] = (short)f2bf(lo[1]);
  v[2] = (short)f2bf(lo[2]); v[3] = (short)f2bf(lo[3]);
  v[4] = (short)f2bf(hi[0]); v[5] = (short)f2bf(hi[1]);
  v[6] = (short)f2bf(hi[2]); v[7] = (short)f2bf(hi[3]);
  *(short8*)(wb + dst + (size_t)threadIdx.x * 8) = v;
}

// ---------------- one LSTM layer: 4 waves = 4 K-quarters, 16 dims/WG ----------------
// Ring slot s (phys s%RING): [64][2048]: cols 0-1023 = h1(s-1), 1024-2047 = h0(s-1).
// L0 step t: reads slot[t] hi + xs[t]; writes slot[t+1] hi; canary (t*2+0).
// L1 step t: kq 0-1 read slot[t] lo (h1(t-1)); kq 2-3 read slot[t+1] hi (h0(t));
//            writes slot[t+1] lo; canary (t*2+1).
// Weights: bf16 from wb; first KTV k-tiles VGPR-resident, rest streamed from L2.
template<int LAYER>
__device__ __forceinline__ void run_layer(
    const unsigned short* __restrict__ xs_all,
    unsigned short* __restrict__ state,
    unsigned* __restrict__ can,
    const unsigned short* __restrict__ wb,
    const float* __restrict__ B0, const float* __restrict__ B1,
    const float* __restrict__ B2, const float* __restrict__ B3,
    float* buf, int w, int tid)
{
  constexpr int K   = LAYER ? 2048 : 1536;
  constexpr int KT  = K / 128;             // 16 / 12 K-tiles per wave
  constexpr int KTV = 6;                   // VGPR-resident K-tiles (96 VGPR)
  const int lane = tid & 63;
  const int wid  = tid >> 6;               // wave id = K-quarter
  const int ln   = lane & 15;
  const int qq   = lane >> 4;
  const int d0   = (tid & 7) * 2;          // dim pair within WG's 16 dims
  const int bp   = (tid >> 3) * 2;         // batch pair
  const int gk0  = w * 16 + d0;

  // weight row pointers (bf16, row = dim w*16+ln of gate mt)
  const unsigned short* wrow[4];
  #pragma unroll
  for (int mt = 0; mt < 4; ++mt)
    wrow[mt] = wb + (LAYER ? (size_t)L1OFF + (size_t)mt * L1G
                           : (size_t)mt * L0G)
                  + (size_t)(w * 16 + ln) * K;

  auto colw = [&](int kt) {
    int c;
    if (LAYER == 1) c = wid * 512 + kt * 32;
    else c = (kt < 4) ? (1024 + wid * 128 + kt * 32) : (wid * 256 + (kt - 4) * 32);
    return c + qq * 8;
  };

  short8 wreg[KTV][4];
  #pragma unroll
  for (int kt = 0; kt < KTV; ++kt)
    #pragma unroll
    for (int mt = 0; mt < 4; ++mt)
      wreg[kt][mt] = *(const short8*)(wrow[mt] + colw(kt));

  float bs[4][2];
  #pragma unroll
  for (int g = 0; g < 4; ++g) {
    const float* Bg = (g == 0) ? B0 : (g == 1) ? B1 : (g == 2) ? B2 : B3;
    bs[g][0] = Bg[gk0]; bs[g][1] = Bg[gk0 + 1];
  }
  float cst[2][2] = {{0.f, 0.f}, {0.f, 0.f}};

  for (int t = 0; t < T_SEQ; ++t) {
    const unsigned short* slotT  = state + (size_t)(t % RING) * SLOT_E;
    unsigned short*       slotT1 = state + (size_t)((t + 1) % RING) * SLOT_E;

    bool war_ok = true;                    // L0 ring-WAR prefetch
    if (LAYER == 0 && t >= RB) {
      unsigned v = __hip_atomic_load(can + (((t - RB) * 2 + 1) << 6) + lane,
                                     __ATOMIC_RELAXED, AGENT);
      war_ok = !__any(v == SENT);
    }

    f32x4 acc[4][4] = {};
    if constexpr (LAYER == 0) {
      // x-phase (static, cacheable) overlaps the canary-poll latency
      const unsigned short* xrow = xs_all + (size_t)t * (NBATCH * EMBED);
      #pragma unroll
      for (int kt = 0; kt < 4; ++kt) {
        const int bc = wid * 128 + kt * 32 + qq * 8;
        short8 bf[4];
        #pragma unroll
        for (int nt = 0; nt < 4; ++nt)
          bf[nt] = *(const short8*)(xrow + (size_t)(nt * 16 + ln) * EMBED + bc);
        #pragma unroll
        for (int mt = 0; mt < 4; ++mt)
          #pragma unroll
          for (int nt = 0; nt < 4; ++nt)
            acc[mt][nt] = __builtin_amdgcn_mfma_f32_16x16x32_bf16(
                wreg[kt][mt], bf[nt], acc[mt][nt], 0, 0, 0);
      }
      if (t > 0) pollcan(can, (t - 1) * 2 + 0, lane);   // h0(t-1) ready
      const unsigned short* hb = slotT + 1024;
      #pragma unroll
      for (int kt = 4; kt < KT; ++kt) {
        const int col = colw(kt);
        short8 wf[4];
        #pragma unroll
        for (int mt = 0; mt < 4; ++mt)
          wf[mt] = (kt < KTV) ? wreg[kt < KTV ? kt : 0][mt]
                              : *(const short8*)(wrow[mt] + col);
        const int hc = wid * 256 + (kt - 4) * 32 + qq * 8;
        short8 bf[4];
        #pragma unroll
        for (int nt = 0; nt < 4; ++nt)
          bf[nt] = ldb16(hb + (size_t)(nt * 16 + ln) * 2048 + hc);
        #pragma unroll
        for (int mt = 0; mt < 4; ++mt)
          #pragma unroll
          for (int nt = 0; nt < 4; ++nt)
            acc[mt][nt] = __builtin_amdgcn_mfma_f32_16x16x32_bf16(
                wf[mt], bf[nt], acc[mt][nt], 0, 0, 0);
      }
    } else {
      if (wid < 2) { if (t > 0) pollcan(can, (t - 1) * 2 + 1, lane); }
      else         { pollcan(can, t * 2 + 0, lane); }
      const unsigned short* base = (wid < 2) ? slotT : slotT1;
      #pragma unroll
      for (int kt = 0; kt < KT; ++kt) {
        const int col = colw(kt);            // also the column inside the slot
        short8 wf[4];
        #pragma unroll
        for (int mt = 0; mt < 4; ++mt)
          wf[mt] = (kt < KTV) ? wreg[kt < KTV ? kt : 0][mt]
                              : *(const short8*)(wrow[mt] + col);
        short8 bf[4];
        #pragma unroll
        for (int nt = 0; nt < 4; ++nt)
          bf[nt] = ldb16(base + (size_t)(nt * 16 + ln) * 2048 + col);
        #pragma unroll
        for (int mt = 0; mt < 4; ++mt)
          #pragma unroll
          for (int nt = 0; nt < 4; ++nt)
            acc[mt][nt] = __builtin_amdgcn_mfma_f32_16x16x32_bf16(
                wf[mt], bf[nt], acc[mt][nt], 0, 0, 0);
      }
    }

    // ---- each wave writes its K-partial to its own LDS buffer ----
    {
      float* bb = buf + wid * PBUF;
      #pragma unroll
      for (int mt = 0; mt < 4; ++mt)
        #pragma unroll
        for (int nt = 0; nt < 4; ++nt)
          #pragma unroll
          for (int j = 0; j < 4; ++j)
            bb[(mt * 16 + qq * 4 + j) * RST + nt * 16 + ln] = acc[mt][nt][j];
    }
    __syncthreads();

    // ---- gate math: dims (gk0, gk0+1) x batches (bp, bp+1) ----
    float gv[4][2][2];
    #pragma unroll
    for (int gt = 0; gt < 4; ++gt)
      #pragma unroll
      for (int dd = 0; dd < 2; ++dd) {
        float sx = bs[gt][dd], sy = bs[gt][dd];
        #pragma unroll
        for (int p = 0; p < 4; ++p) {
          float2 v = *(const float2*)&buf[p * PBUF + (gt * 16 + d0 + dd) * RST + bp];
          sx += v.x; sy += v.y;
        }
        gv[gt][dd][0] = sx; gv[gt][dd][1] = sy;
      }

    if (LAYER == 0 && t >= RB && !war_ok)
      pollcan(can, (t - RB) * 2 + 1, lane);  // ring WAR: L1@(t-RB) done reading

    unsigned* su = (unsigned*)state;
    const size_t obase = (size_t)((t + 1) % RING) * SLOT_E
                       + (LAYER == 0 ? 1024 : 0) + gk0;
    #pragma unroll
    for (int s2 = 0; s2 < 2; ++s2) {
      cst[0][s2] = sigm(gv[0][0][s2]) * cst[0][s2] + sigm(gv[1][0][s2]) * tanh_(gv[3][0][s2]);
      cst[1][s2] = sigm(gv[0][1][s2]) * cst[1][s2] + sigm(gv[1][1][s2]) * tanh_(gv[3][1][s2]);
      const float h0v = sigm(gv[2][0][s2]) * tanh_(cst[0][s2]);
      const float h1v = sigm(gv[2][1][s2]) * tanh_(cst[1][s2]);
      const unsigned pk = (unsigned)f2bf(h0v) | ((unsigned)f2bf(h1v) << 16);
      __hip_atomic_store(su + ((obase + (size_t)(bp + s2) * 2048) >> 1), pk,
                         __ATOMIC_RELAXED, AGENT);
    }
    asm volatile("s_waitcnt vmcnt(0)" ::: "memory");  // h-stores acked at MALL
    __syncthreads();                                  // all 4 waves drained
    if (tid == 0)
      __hip_atomic_store(can + ((t * 2 + LAYER) << 6) + w, 0u,
                         __ATOMIC_RELAXED, AGENT);    // canary AFTER data
  }
}

__launch_bounds__(NTHR, 1)
__global__ void lstm_k(const unsigned short* __restrict__ xs,
                       unsigned short* __restrict__ state,
                       unsigned* __restrict__ can,
                       const unsigned short* __restrict__ wb,
                       const float* __restrict__ bf0, const float* __restrict__ bi0,
                       const float* __restrict__ bo0, const float* __restrict__ bc0,
                       const float* __restrict__ bf1, const float* __restrict__ bi1,
                       const float* __restrict__ bo1, const float* __restrict__ bc1)
{
  __shared__ __align__(16) float buf[4 * PBUF];   // 67.6 KB
  const int tid = threadIdx.x;
  const int gw  = blockIdx.x;
  if (gw < 64)
    run_layer<0>(xs, state, can, wb, bf0, bi0, bo0, bc0, buf, gw, tid);
  else
    run_layer<1>(nullptr, state, can, wb, bf1, bi1, bo1, bc1, buf, gw - 64, tid);
}

// ---------------- final projection: y[b][v] = h1(511) . Wy[v] + by[v] ----------------
__global__ void final_k(const float* __restrict__ Wy,                // [VOCAB][1024] f32
                        const unsigned short* __restrict__ hlast,    // [64][2048] lo-half
                        const float* __restrict__ by,
                        float* __restrict__ out)                     // [64][VOCAB] f32
{
  const int tid = threadIdx.x, lane = tid & 63, wid = tid >> 6;
  const int ln = lane & 15, qq = lane >> 4;
  const int vbase = (blockIdx.x * 4 + wid) * 16;
  f32x4 acc[4] = {};
  const float* arow = Wy + (size_t)(vbase + ln) * HIDDEN;
  for (int kt = 0; kt < 32; ++kt) {
    const int kk = kt * 32 + qq * 8;
    f32x4 lo = *(const f32x4*)(arow + kk);
    f32x4 hi = *(const f32x4*)(arow + kk + 4);
    short8 a;
    a[0] = (short)f2bf(lo[0]); a[1] = (short)f2bf(lo[1]);
    a[2] = (short)f2bf(lo[2]); a[3] = (short)f2bf(lo[3]);
    a[4] = (short)f2bf(hi[0]); a[5] = (short)f2bf(hi[1]);
    a[6] = (short)f2bf(hi[2]); a[7] = (short)f2bf(hi[3]);
    #pragma unroll
    for (int nt = 0; nt < 4; ++nt) {
      short8 bv = *(const short8*)(hlast + (size_t)(nt * 16 + ln) * 2048 + kk);
      acc[nt] = __builtin_amdgcn_mfma_f32_16x16x32_bf16(a, bv, acc[nt], 0, 0, 0);
    }
  }
  const int v0 = vbase + qq * 4;
  const f32x4 bias = *(const f32x4*)(by + v0);
  #pragma unroll
  for (int nt = 0; nt < 4; ++nt) {
    const int bb = nt * 16 + ln;
    f32x4 r = acc[nt] + bias;
    *(f32x4*)(out + (size_t)bb * VOCAB + v0) = r;
  }
}

// ---------------- host ----------------
extern "C" void kernel_launch(void* const* d_in, const int* in_sizes, int n_in,
                              void* d_out, int out_size, void* d_ws, size_t ws_size,
                              hipStream_t stream) {
  (void)in_sizes; (void)n_in; (void)out_size; (void)ws_size;
  const int*   texts = (const int*)d_in[0];
  const float* emb   = (const float*)d_in[1];
  const float* Wf0 = (const float*)d_in[2];  const float* bf0 = (const float*)d_in[3];
  const float* Wi0 = (const float*)d_in[4];  const float* bi0 = (const float*)d_in[5];
  const float* Wo0 = (const float*)d_in[6];  const float* bo0 = (const float*)d_in[7];
  const float* Wc0 = (const float*)d_in[8];  const float* bc0 = (const float*)d_in[9];
  const float* Wf1 = (const float*)d_in[10]; const float* bf1 = (const float*)d_in[11];
  const float* Wi1 = (const float*)d_in[12]; const float* bi1 = (const float*)d_in[13];
  const float* Wo1 = (const float*)d_in[14]; const float* bo1 = (const float*)d_in[15];
  const float* Wc1 = (const float*)d_in[16]; const float* bc1 = (const float*)d_in[17];
  const float* Wy  = (const float*)d_in[18]; const float* by  = (const float*)d_in[19];

  char* ws = (char*)d_ws;
  // ws layout (bytes):
  // [0]          can   512*2*64*4      = 262,144   (memset 0xFF each launch)
  // [262,144]    state RING*SLOT_E*2   = 33,554,432 (slot 0 memset 0 each launch)
  // [33,816,576] xs    512*64*512*2    = 33,554,432
  // [67,371,008] wb    14,680,064*2    = 29,360,128  -> end 96,731,136
  unsigned*       can   = (unsigned*)ws;
  unsigned short* state = (unsigned short*)(ws + 262144);
  unsigned short* xs    = (unsigned short*)(ws + 33816576);
  unsigned short* wb    = (unsigned short*)(ws + 67371008);
  float* out = (float*)d_out;

  hipMemsetAsync(can, 0xFF, 262144, stream);          // canaries = not-ready
  hipMemsetAsync(state, 0, SLOT_E * 2, stream);       // phys slot 0 = h(-1) zeros
  embed_k<<<T_SEQ * NBATCH, 256, 0, stream>>>(texts, emb, xs);
  wcast_k<<<7168, 256, 0, stream>>>(Wf0, Wi0, Wo0, Wc0, Wf1, Wi1, Wo1, Wc1, wb);
  lstm_k<<<NWG, NTHR, 0, stream>>>(xs, state, can, wb,
                                   bf0, bi0, bo0, bc0, bf1, bi1, bo1, bc1);
  // h1(511) lives in slot 512 % RING = 0, cols 0..1023
  final_k<<<VOCAB / 64, 256, 0, stream>>>(Wy, state, by, out);
}